// Round 8
// baseline (694.457 us; speedup 1.0000x reference)
//
#include <hip/hip_runtime.h>

// ---------------------------------------------------------------------------
// OracleAD2D: per-variable LSTM encoder -> temporal softmax pooling -> MHSA
//             -> per-variable LSTM decoder.  B=64, L=128, N=32, D=128, H=4.
//
// Round-8 (= round-7 + C_star output fix):
//  * C_star is the 3rd OUTPUT of the reference -- dec's inline out-projection
//    now also stores the projected C_star to its output region (r7 left raw
//    attention A there -> Output 2 absmax 0.28).  In-place safe: A reads
//    complete at the staging barrier; blocks touch disjoint (b,n) slices.
//  * 3 kernels: enc, attn, dec(+outproj).  256 blocks each for enc/dec
//    (32 n x 8 b-tiles of 8), XCD swizzle n=blk&31, Whh resident as f16
//    B-fragments, 1 intra-block barrier/step.
//  * Pool/out dot split into 4 un-chained MFMAs (waves 0-3, K-chunk each,
//    f32 partials in LDS) -- no per-step wave-0 straggler.
//  * Zero-row broadcast: A-frag lanes for rows =2,3 mod 4 (always zero)
//    read one shared zero row -> post-barrier LDS burst ~halved.
//  * MFMA layouts (m89/m91/m120-verified on gfx950):
//      A: lane holds A[m = lane&15][k = (lane>>4)*8 + j]   (8 f16)
//      B: lane holds B[n = lane&15][k = (lane>>4)*8 + j]   (8 f16)
//      D: lane reg r holds D[row = (lane>>4)*4 + r][col = lane&15]
// ---------------------------------------------------------------------------

typedef _Float16 h8  __attribute__((ext_vector_type(8)));
typedef _Float16 h4v __attribute__((ext_vector_type(4)));
typedef float    f4  __attribute__((ext_vector_type(4)));
typedef float    f2v __attribute__((ext_vector_type(2)));

#define DI __device__ __forceinline__

constexpr int NV  = 32;          // variables
constexpr int LT  = 128;         // sequence length
constexpr int DH  = 128;         // hidden
constexpr int GG  = 4 * DH;      // 512 gate rows
constexpr int BR  = 8;           // batch rows per block (enc/dec)
constexpr int NW  = 8;           // waves per block
constexpr int TPB = NW * 64;     // 512 threads
constexpr int HSTR = DH + 8;     // padded f16 row stride (16B-aligned)
constexpr float LOG2E = 1.4426950408889634f;

DI float rcp_(float x) { return __builtin_amdgcn_rcpf(x); }
DI float ex2_(float x) { return __builtin_amdgcn_exp2f(x); }

DI float tanh_(float x) {
    float xc = fminf(fmaxf(x, -20.0f), 20.0f);
    float E = ex2_(2.0f * LOG2E * xc);                  // e^{2x}
    return (E - 1.0f) * rcp_(E + 1.0f);
}

// Pre-scaled LSTM cell (scales folded into weights):
//   iv = -log2e*i, fv = -log2e*f, gv = 2log2e*g, ov = -log2e*o
DI float lstm_cell(float iv, float fv, float gv, float ov, float& c) {
    float Ai = ex2_(iv);                 // e^{-i}
    float Af = ex2_(fv);                 // e^{-f}
    float Bg = ex2_(gv);                 // e^{2g}
    float ai1 = 1.0f + Ai, af1 = 1.0f + Af, bg1 = 1.0f + Bg;
    float P = ai1 * bg1;
    float N = fmaf(c, P, (Bg - 1.0f) * af1);
    c = N * rcp_(P * af1);
    float cc = fminf(fmaxf(c, -20.0f), 20.0f);
    float Ec = ex2_(2.0f * LOG2E * cc);  // e^{2c}
    float Eo = ex2_(ov);                 // e^{-o}
    return (Ec - 1.0f) * rcp_((1.0f + Eo) * (1.0f + Ec)); // sig(o)*tanh(c)
}

DI h8 cvt8(f4 a, f4 b) {
    h8 r;
    r[0] = (_Float16)a[0]; r[1] = (_Float16)a[1];
    r[2] = (_Float16)a[2]; r[3] = (_Float16)a[3];
    r[4] = (_Float16)b[0]; r[5] = (_Float16)b[1];
    r[6] = (_Float16)b[2]; r[7] = (_Float16)b[3];
    return r;
}
DI h8 cvt8s(f4 a, f4 b, float s) {
    h8 r;
    r[0] = (_Float16)(a[0] * s); r[1] = (_Float16)(a[1] * s);
    r[2] = (_Float16)(a[2] * s); r[3] = (_Float16)(a[3] * s);
    r[4] = (_Float16)(b[0] * s); r[5] = (_Float16)(b[1] * s);
    r[6] = (_Float16)(b[2] * s); r[7] = (_Float16)(b[3] * s);
    return r;
}

// gate exp2 scales (torch order i,f,g,o)
__constant__ float GSC[4] = {-LOG2E, -LOG2E, 2.0f * LOG2E, -LOG2E};

// ---------------------------------------------------------------------------
// Encoder: 127 LSTM steps + online softmax pooling.  Writes C (B,N,D) f32.
// ---------------------------------------------------------------------------
__global__ __launch_bounds__(TPB, 2)
void enc_kernel(const float* __restrict__ X,      // (B,L,N)
                const float* __restrict__ Wih,    // (N,512)
                const float* __restrict__ Whh,    // (N,512,128)
                const float* __restrict__ bih,    // (N,512)
                const float* __restrict__ bhh,    // (N,512)
                const float* __restrict__ poolw,  // (N,128)
                float* __restrict__ Cout)         // (B,N,D)
{
    const int n    = blockIdx.x & 31;           // XCD swizzle: same n -> same XCD
    const int b0   = (blockIdx.x >> 5) * BR;
    const int tid  = threadIdx.x;
    const int wv   = tid >> 6;
    const int lane = tid & 63;
    const int quad = lane >> 4;
    const int l16  = lane & 15;
    const int dmy  = wv * 16 + l16;
    // zero-row broadcast: rows =2,3 mod 4 are always zero -> read shared row 2
    const int rowA = ((l16 & 3) < 2) ? l16 : 2;

    __shared__ _Float16 hbuf[2][16 * HSTR];
    __shared__ float xs[(LT - 1) * BR];
    __shared__ float sred[2][BR][4];            // pool partials (4 K-chunks)

    // --- preload B-fragments of Whh (f16, scaled by gate exp2 factor) ---
    h8 Wf[4][4];
    float wihr[4];
    f4 bsp[4];
#pragma unroll
    for (int g4 = 0; g4 < 4; ++g4) {
        const float s = GSC[g4];
        const int g = g4 * DH + dmy;
        const float* wrow = Whh + (size_t)(n * GG + g) * DH;
#pragma unroll
        for (int kc = 0; kc < 4; ++kc) {
            f4 w0 = *(const f4*)(wrow + kc * 32 + quad * 8);
            f4 w1 = *(const f4*)(wrow + kc * 32 + quad * 8 + 4);
            Wf[g4][kc] = cvt8s(w0, w1, s);
        }
        wihr[g4] = Wih[n * GG + g] * s;
        const float bb = (bih[n * GG + g] + bhh[n * GG + g]) * s;
        bsp[g4] = (f4){bb, bb, bb, bb};
    }
    // pool K-chunk fragment for waves 0-3: chunk wv, col 0 = pool_w * log2e
    h8 Bp = (h8)(_Float16)0.0f;
    if (wv < 4 && l16 == 0) {
        f4 p0 = *(const f4*)(poolw + n * DH + wv * 32 + quad * 8);
        f4 p1 = *(const f4*)(poolw + n * DH + wv * 32 + quad * 8 + 4);
        Bp = cvt8s(p0, p1, LOG2E);
    }
    const f4 z4 = {0.f, 0.f, 0.f, 0.f};

    // --- stage X slab (8 b x 127 t) and zero both h buffers ---
    for (int i = tid; i < (LT - 1) * BR; i += TPB)      // i = t*8 + b
        xs[i] = X[((size_t)(b0 + (i & 7)) * LT + (i >> 3)) * NV + n];
    for (int i = tid; i < 2 * 16 * HSTR; i += TPB)
        ((_Float16*)hbuf)[i] = (_Float16)0.0f;
    __syncthreads();

    float cst[2]   = {0.f, 0.f};
    float lsum[2]  = {0.f, 0.f};
    float acc[2]   = {0.f, 0.f};
    float hprev[2] = {0.f, 0.f};

    for (int t = 0; t < LT - 1; ++t) {
        const _Float16* ab = hbuf[t & 1] + rowA * HSTR + quad * 8;
        h8 a[4];
#pragma unroll
        for (int kc = 0; kc < 4; ++kc)
            a[kc] = *(const h8*)(ab + kc * 32);

        f4 pre[4];
#pragma unroll
        for (int g4 = 0; g4 < 4; ++g4)
            pre[g4] = __builtin_amdgcn_mfma_f32_16x16x32_f16(
                a[0], Wf[g4][0], bsp[g4], 0, 0, 0);
#pragma unroll
        for (int kc = 1; kc < 4; ++kc)
#pragma unroll
            for (int g4 = 0; g4 < 4; ++g4)
                pre[g4] = __builtin_amdgcn_mfma_f32_16x16x32_f16(
                    a[kc], Wf[g4][kc], pre[g4], 0, 0, 0);

        // pool partial: waves 0-3, one UN-chained MFMA each (K-chunk wv)
        if (wv < 4) {
            f4 sp = __builtin_amdgcn_mfma_f32_16x16x32_f16(a[wv], Bp, z4, 0, 0, 0);
            if (l16 == 0) {
                sred[t & 1][quad * 2 + 0][wv] = sp[0];
                sred[t & 1][quad * 2 + 1][wv] = sp[1];
            }
        }

        const f2v xv = *(const f2v*)(xs + t * BR + quad * 2);
        float hv[2];
#pragma unroll
        for (int r = 0; r < 2; ++r) {
            hv[r] = lstm_cell(fmaf(xv[r], wihr[0], pre[0][r]),
                              fmaf(xv[r], wihr[1], pre[1][r]),
                              fmaf(xv[r], wihr[2], pre[2][r]),
                              fmaf(xv[r], wihr[3], pre[3][r]), cst[r]);
        }

        _Float16* hn = hbuf[(t + 1) & 1];
#pragma unroll
        for (int r = 0; r < 2; ++r)
            hn[(quad * 4 + r) * HSTR + dmy] = (_Float16)hv[r];
        __syncthreads();

        // pooling update: sum 4 partials + exp (all lanes; broadcast reads)
        if (t > 0) {
#pragma unroll
            for (int r = 0; r < 2; ++r) {
                const f4 s4 = *(const f4*)&sred[t & 1][quad * 2 + r][0];
                const float p = ex2_((s4[0] + s4[1]) + (s4[2] + s4[3]));
                lsum[r] += p;
                acc[r] = fmaf(p, hprev[r], acc[r]);
            }
        }
#pragma unroll
        for (int r = 0; r < 2; ++r) hprev[r] = hv[r];
    }

    // tail: pool weight for h^(127) (staged in hbuf[(LT-1)&1])
    if (wv < 4) {
        h8 at = *(const h8*)(hbuf[(LT - 1) & 1] + rowA * HSTR + wv * 32 + quad * 8);
        f4 sp = __builtin_amdgcn_mfma_f32_16x16x32_f16(at, Bp, z4, 0, 0, 0);
        if (l16 == 0) {
            sred[(LT - 1) & 1][quad * 2 + 0][wv] = sp[0];
            sred[(LT - 1) & 1][quad * 2 + 1][wv] = sp[1];
        }
    }
    __syncthreads();
#pragma unroll
    for (int r = 0; r < 2; ++r) {
        const f4 s4 = *(const f4*)&sred[(LT - 1) & 1][quad * 2 + r][0];
        const float p = ex2_((s4[0] + s4[1]) + (s4[2] + s4[3]));
        lsum[r] += p;
        acc[r] = fmaf(p, hprev[r], acc[r]);
    }
#pragma unroll
    for (int r = 0; r < 2; ++r) {
        const int b = b0 + quad * 2 + r;
        Cout[((size_t)b * NV + n) * DH + dmy] = acc[r] * rcp_(lsum[r]);
    }
}

// ---------------------------------------------------------------------------
// Fused attention: one block per (b, head).  qkv proj + scores + softmax + PV
// all via MFMA.  Writes A (B,N,D) f32 (heads concatenated) to Astage.
// ---------------------------------------------------------------------------
constexpr int CS2 = DH + 8;     // f16 stride for staged C (16B-aligned rows)
constexpr int QS  = 40;         // f16 stride for q/k/vT/P (80 B rows, aligned)

__global__ __launch_bounds__(256)
void attn_kernel(const float* __restrict__ Cin,   // (B,N,D)
                 const float* __restrict__ Wqkv,  // (384,128)
                 const float* __restrict__ bqkv,  // (384)
                 float* __restrict__ Astage)      // (B,N,D)
{
    const int b    = blockIdx.x >> 2;
    const int hh   = blockIdx.x & 3;
    const int tid  = threadIdx.x;
    const int wv   = tid >> 6;          // 4 waves
    const int lane = tid & 63;
    const int quad = lane >> 4;
    const int l16  = lane & 15;

    __shared__ _Float16 Cb[NV][CS2];    // C tokens as f16 (A-operand layout)
    __shared__ _Float16 qs[NV][QS], ks[NV][QS], vT[NV][QS];
    __shared__ float    S[NV][NV + 1];
    __shared__ _Float16 P[NV][QS];

    // stage C[b] -> f16 LDS
    for (int i = tid; i < NV * DH / 4; i += 256) {
        const int nn = i >> 5, d4 = (i & 31) * 4;
        f4 v = *(const f4*)(Cin + ((size_t)b * NV + nn) * DH + d4);
        h4v hv4;
        hv4[0] = (_Float16)v[0]; hv4[1] = (_Float16)v[1];
        hv4[2] = (_Float16)v[2]; hv4[3] = (_Float16)v[3];
        *(h4v*)(&Cb[nn][d4]) = hv4;
    }
    __syncthreads();

    // --- qkv: wave wv computes sub-tile (m0,n0) of each of q, k, v ---
    const int m0 = (wv >> 1) * 16;      // token tile
    const int n0 = (wv & 1) * 16;       // column tile (within the head's 32)

    h8 a[4];
#pragma unroll
    for (int kc = 0; kc < 4; ++kc)
        a[kc] = *(const h8*)(&Cb[m0 + l16][kc * 32 + quad * 8]);

#pragma unroll
    for (int mat = 0; mat < 3; ++mat) {      // 0=q, 1=k, 2=v
        const int rbase = mat * DH + hh * 32;
        const float* wrow = Wqkv + (size_t)(rbase + n0 + l16) * DH;
        const float bias  = bqkv[rbase + n0 + l16];
        f4 acc = {bias, bias, bias, bias};
#pragma unroll
        for (int kc = 0; kc < 4; ++kc) {
            f4 w0 = *(const f4*)(wrow + kc * 32 + quad * 8);
            f4 w1 = *(const f4*)(wrow + kc * 32 + quad * 8 + 4);
            acc = __builtin_amdgcn_mfma_f32_16x16x32_f16(a[kc], cvt8(w0, w1), acc, 0, 0, 0);
        }
#pragma unroll
        for (int r = 0; r < 4; ++r) {
            const int tok = m0 + quad * 4 + r, col = n0 + l16;
            if (mat == 0)      qs[tok][col] = (_Float16)acc[r];
            else if (mat == 1) ks[tok][col] = (_Float16)acc[r];
            else               vT[col][tok] = (_Float16)acc[r];   // transposed
        }
    }
    __syncthreads();

    // --- scores: wave wv -> S tile (m0, n0), K = 32 head dims ---
    {
        h8 aq = *(const h8*)(&qs[m0 + l16][quad * 8]);
        h8 bk = *(const h8*)(&ks[n0 + l16][quad * 8]);
        f4 sc = {0.f, 0.f, 0.f, 0.f};
        sc = __builtin_amdgcn_mfma_f32_16x16x32_f16(aq, bk, sc, 0, 0, 0);
#pragma unroll
        for (int r = 0; r < 4; ++r)
            S[m0 + quad * 4 + r][n0 + l16] = sc[r] * 0.17677669529663687f; // 1/sqrt(32)
    }
    __syncthreads();

    // --- softmax per query row (32 threads) ---
    if (tid < NV) {
        float mx = -1e30f;
        for (int j = 0; j < NV; ++j) mx = fmaxf(mx, S[tid][j]);
        float l = 0.0f;
        float p[NV];
#pragma unroll
        for (int j = 0; j < NV; ++j) {
            p[j] = ex2_(LOG2E * (S[tid][j] - mx));
            l += p[j];
        }
        const float rl = rcp_(l);
#pragma unroll
        for (int j = 0; j < NV; ++j) P[tid][j] = (_Float16)(p[j] * rl);
    }
    __syncthreads();

    // --- PV: wave wv -> A tile (m0, n0), K = 32 keys ---
    {
        h8 ap = *(const h8*)(&P[m0 + l16][quad * 8]);
        h8 bv = *(const h8*)(&vT[n0 + l16][quad * 8]);
        f4 av = {0.f, 0.f, 0.f, 0.f};
        av = __builtin_amdgcn_mfma_f32_16x16x32_f16(ap, bv, av, 0, 0, 0);
#pragma unroll
        for (int r = 0; r < 4; ++r) {
            const int tok = m0 + quad * 4 + r;
            Astage[((size_t)b * NV + tok) * DH + hh * 32 + n0 + l16] = av[r];
        }
    }
}

// ---------------------------------------------------------------------------
// Decoder: inline out-projection (C* = A@Wo^T + bo; stored to the C_star
// OUTPUT region and fed to the LSTM), init h/c = tanh(Linear(C*)), 128
// zero-input LSTM steps; output dot split across waves 0-3; recon buffered
// in LDS, bulk-written after the loop.
// ---------------------------------------------------------------------------
__global__ __launch_bounds__(TPB, 2)
void dec_kernel(const float* __restrict__ A,      // (B,N,D) attention output
                float* __restrict__ Cst,          // (B,N,D) C_star OUTPUT (=A region)
                const float* __restrict__ Wo,     // (128,128)
                const float* __restrict__ bo,     // (128)
                const float* __restrict__ ihW,    // (N,D,D)
                const float* __restrict__ ihb,    // (N,D)
                const float* __restrict__ icW,    // (N,D,D)
                const float* __restrict__ icb,    // (N,D)
                const float* __restrict__ Whh,    // (N,512,128)
                const float* __restrict__ bih,    // (N,512)
                const float* __restrict__ bhh,    // (N,512)
                const float* __restrict__ outW,   // (N,128)
                const float* __restrict__ outb,   // (N)
                float* __restrict__ recon,        // (B,127,N)
                float* __restrict__ pred)         // (B,N)
{
    const int n    = blockIdx.x & 31;           // XCD swizzle
    const int b0   = (blockIdx.x >> 5) * BR;
    const int tid  = threadIdx.x;
    const int wv   = tid >> 6;
    const int lane = tid & 63;
    const int quad = lane >> 4;
    const int l16  = lane & 15;
    const int dmy  = wv * 16 + l16;
    const int rowA = ((l16 & 3) < 2) ? l16 : 2;  // zero-row broadcast

    __shared__ _Float16 hbuf[2][16 * HSTR];
    __shared__ float obuf[LT - 1][BR];
    __shared__ float sred[2][BR][4];             // out-dot partials

    h8 Wf[4][4];
    f4 bsp[4];
#pragma unroll
    for (int g4 = 0; g4 < 4; ++g4) {
        const float s = GSC[g4];
        const int g = g4 * DH + dmy;
        const float* wrow = Whh + (size_t)(n * GG + g) * DH;
#pragma unroll
        for (int kc = 0; kc < 4; ++kc) {
            f4 w0 = *(const f4*)(wrow + kc * 32 + quad * 8);
            f4 w1 = *(const f4*)(wrow + kc * 32 + quad * 8 + 4);
            Wf[g4][kc] = cvt8s(w0, w1, s);
        }
        const float bb = (bih[n * GG + g] + bhh[n * GG + g]) * s;
        bsp[g4] = (f4){bb, bb, bb, bb};
    }
    // out-dot K-chunk fragment for waves 0-3 (col 0 = out_W, true scale)
    h8 Bo = (h8)(_Float16)0.0f;
    if (wv < 4 && l16 == 0) {
        f4 p0 = *(const f4*)(outW + n * DH + wv * 32 + quad * 8);
        f4 p1 = *(const f4*)(outW + n * DH + wv * 32 + quad * 8 + 4);
        Bo = cvt8(p0, p1);
    }
    const float ob = outb[n];
    const f4 z4 = {0.f, 0.f, 0.f, 0.f};

    // --- zero both h buffers; stage A rows (8 b) at rows (j>>1)*4+(j&1) ---
    for (int i = tid; i < 2 * 16 * HSTR; i += TPB)
        ((_Float16*)hbuf)[i] = (_Float16)0.0f;
    __syncthreads();
    if (tid < 256) {
        const int j = tid >> 5, d4 = (tid & 31) * 4;    // 8 rows x 32 f4
        const int row = (j >> 1) * 4 + (j & 1);
        f4 v = *(const f4*)(A + ((size_t)(b0 + j) * NV + n) * DH + d4);
        h4v hv4;
        hv4[0] = (_Float16)v[0]; hv4[1] = (_Float16)v[1];
        hv4[2] = (_Float16)v[2]; hv4[3] = (_Float16)v[3];
        *(h4v*)(&hbuf[0][row * HSTR + d4]) = hv4;
    }
    __syncthreads();

    // --- inline out-projection: cs = A @ Wo^T + bo -> hbuf[1] (f16) and
    //     the C_star OUTPUT region (f32).  In-place on the A region: all A
    //     reads finished at the staging barrier above. ---
    {
        const _Float16* ab = hbuf[0] + rowA * HSTR + quad * 8;
        h8 a[4];
#pragma unroll
        for (int kc = 0; kc < 4; ++kc)
            a[kc] = *(const h8*)(ab + kc * 32);
        const float bias = bo[dmy];
        f4 acc = {bias, bias, bias, bias};
        const float* wrow = Wo + (size_t)dmy * DH;
#pragma unroll
        for (int kc = 0; kc < 4; ++kc) {
            f4 w0 = *(const f4*)(wrow + kc * 32 + quad * 8);
            f4 w1 = *(const f4*)(wrow + kc * 32 + quad * 8 + 4);
            acc = __builtin_amdgcn_mfma_f32_16x16x32_f16(a[kc], cvt8(w0, w1), acc, 0, 0, 0);
        }
        __syncthreads();             // all A reads done before hbuf[1] write
#pragma unroll
        for (int r = 0; r < 2; ++r) {
            hbuf[1][(quad * 4 + r) * HSTR + dmy] = (_Float16)acc[r];
            // C_star output store (row quad*4+r holds batch b0+quad*2+r)
            Cst[((size_t)(b0 + quad * 2 + r) * NV + n) * DH + dmy] = acc[r];
        }
    }
    __syncthreads();

    // --- init matmuls: h0 = tanh(cs@ihW^T + ihb), c0 = tanh(cs@icW^T + icb) ---
    float cst[2], hv0[2];
    {
        const _Float16* ab = hbuf[1] + rowA * HSTR + quad * 8;
        h8 a[4];
#pragma unroll
        for (int kc = 0; kc < 4; ++kc)
            a[kc] = *(const h8*)(ab + kc * 32);
        const float bh = ihb[n * DH + dmy];
        const float bc = icb[n * DH + dmy];
        f4 Ph = {bh, bh, bh, bh};
        f4 Pc = {bc, bc, bc, bc};
        const float* hrow = ihW + (size_t)(n * DH + dmy) * DH;
        const float* crow = icW + (size_t)(n * DH + dmy) * DH;
#pragma unroll
        for (int kc = 0; kc < 4; ++kc) {
            f4 w0 = *(const f4*)(hrow + kc * 32 + quad * 8);
            f4 w1 = *(const f4*)(hrow + kc * 32 + quad * 8 + 4);
            Ph = __builtin_amdgcn_mfma_f32_16x16x32_f16(a[kc], cvt8(w0, w1), Ph, 0, 0, 0);
            f4 u0 = *(const f4*)(crow + kc * 32 + quad * 8);
            f4 u1 = *(const f4*)(crow + kc * 32 + quad * 8 + 4);
            Pc = __builtin_amdgcn_mfma_f32_16x16x32_f16(a[kc], cvt8(u0, u1), Pc, 0, 0, 0);
        }
#pragma unroll
        for (int r = 0; r < 2; ++r) {
            hv0[r] = tanh_(Ph[r]);
            cst[r] = tanh_(Pc[r]);
        }
    }
    __syncthreads();                 // all cs reads done before hbuf[0] write
#pragma unroll
    for (int r = 0; r < 2; ++r)
        hbuf[0][(quad * 4 + r) * HSTR + dmy] = (_Float16)hv0[r];
    __syncthreads();

    // --- 128 zero-input LSTM steps; iter t's A-frags are h^(t) ---
    for (int t = 0; t < LT; ++t) {
        const _Float16* ab = hbuf[t & 1] + rowA * HSTR + quad * 8;
        h8 a[4];
#pragma unroll
        for (int kc = 0; kc < 4; ++kc)
            a[kc] = *(const h8*)(ab + kc * 32);

        f4 pre[4];
#pragma unroll
        for (int g4 = 0; g4 < 4; ++g4)
            pre[g4] = __builtin_amdgcn_mfma_f32_16x16x32_f16(
                a[0], Wf[g4][0], bsp[g4], 0, 0, 0);
#pragma unroll
        for (int kc = 1; kc < 4; ++kc)
#pragma unroll
            for (int g4 = 0; g4 < 4; ++g4)
                pre[g4] = __builtin_amdgcn_mfma_f32_16x16x32_f16(
                    a[kc], Wf[g4][kc], pre[g4], 0, 0, 0);

        // out-dot partial: waves 0-3, one un-chained MFMA each
        if (wv < 4) {
            f4 so = __builtin_amdgcn_mfma_f32_16x16x32_f16(a[wv], Bo, z4, 0, 0, 0);
            if (l16 == 0) {
                sred[t & 1][quad * 2 + 0][wv] = so[0];
                sred[t & 1][quad * 2 + 1][wv] = so[1];
            }
        }

        float hv[2];
#pragma unroll
        for (int r = 0; r < 2; ++r)
            hv[r] = lstm_cell(pre[0][r], pre[1][r], pre[2][r], pre[3][r], cst[r]);

        _Float16* hn = hbuf[(t + 1) & 1];
#pragma unroll
        for (int r = 0; r < 2; ++r)
            hn[(quad * 4 + r) * HSTR + dmy] = (_Float16)hv[r];
        __syncthreads();

        if (t > 0 && tid < BR) {
            const f4 s4 = *(const f4*)&sred[t & 1][tid][0];
            obuf[t - 1][tid] = (s4[0] + s4[1]) + (s4[2] + s4[3]) + ob;
        }
    }

    // tail: o^(128) -> pred (h^(128) staged in hbuf[LT & 1] = hbuf[0])
    if (wv < 4) {
        h8 at = *(const h8*)(hbuf[LT & 1] + rowA * HSTR + wv * 32 + quad * 8);
        f4 so = __builtin_amdgcn_mfma_f32_16x16x32_f16(at, Bo, z4, 0, 0, 0);
        if (l16 == 0) {
            sred[LT & 1][quad * 2 + 0][wv] = so[0];
            sred[LT & 1][quad * 2 + 1][wv] = so[1];
        }
    }
    __syncthreads();
    if (tid < BR) {
        const f4 s4 = *(const f4*)&sred[LT & 1][tid][0];
        pred[(size_t)(b0 + tid) * NV + n] = (s4[0] + s4[1]) + (s4[2] + s4[3]) + ob;
    }

    // bulk recon write from obuf (visible via the step-loop barriers)
    if (tid < LT - 1) {
#pragma unroll
        for (int b = 0; b < BR; ++b)
            recon[((size_t)(b0 + b) * (LT - 1) + tid) * NV + n] = obuf[tid][b];
    }
}

// ---------------------------------------------------------------------------
extern "C" void kernel_launch(void* const* d_in, const int* in_sizes, int n_in,
                              void* d_out, int out_size, void* d_ws, size_t ws_size,
                              hipStream_t stream) {
    (void)in_sizes; (void)n_in; (void)d_ws; (void)ws_size; (void)out_size;

    const float* X     = (const float*)d_in[0];
    const float* eWih  = (const float*)d_in[1];
    const float* eWhh  = (const float*)d_in[2];
    const float* ebih  = (const float*)d_in[3];
    const float* ebhh  = (const float*)d_in[4];
    const float* poolw = (const float*)d_in[5];
    // d_in[6] = pool_b: cancels inside softmax over t -> unused
    const float* Wqkv  = (const float*)d_in[7];
    const float* bqkv  = (const float*)d_in[8];
    const float* Wo    = (const float*)d_in[9];
    const float* bo    = (const float*)d_in[10];
    const float* dihW  = (const float*)d_in[11];
    const float* dihb  = (const float*)d_in[12];
    const float* dicW  = (const float*)d_in[13];
    const float* dicb  = (const float*)d_in[14];
    // d_in[15] = dec_Wih: decoder input is identically zero -> unused
    const float* dWhh  = (const float*)d_in[16];
    const float* dbih  = (const float*)d_in[17];
    const float* dbhh  = (const float*)d_in[18];
    const float* doutW = (const float*)d_in[19];
    const float* doutb = (const float*)d_in[20];

    float* out   = (float*)d_out;
    float* recon = out;                              // 64*127*32 = 260096
    float* pred  = out + 64 * 127 * 32;              // 2048
    float* Cstar = out + 64 * 127 * 32 + 64 * 32;    // C_star OUTPUT region
    // Pooled C staged in the recon+pred region; attention output A staged in
    // the C_star region; dec projects A in place (writes the true C_star
    // there) and then overwrites recon/pred.  Ordering via the stream.
    float* Cpool = out;
    float* Astg  = Cstar;

    enc_kernel<<<dim3(256), dim3(TPB), 0, stream>>>(
        X, eWih, eWhh, ebih, ebhh, poolw, Cpool);
    attn_kernel<<<dim3(256), dim3(256), 0, stream>>>(
        Cpool, Wqkv, bqkv, Astg);
    dec_kernel<<<dim3(256), dim3(TPB), 0, stream>>>(
        Astg, Cstar, Wo, bo, dihW, dihb, dicW, dicb, dWhh, dbih, dbhh,
        doutW, doutb, recon, pred);
}

// Round 9
// 292.643 us; speedup vs baseline: 2.3731x; 2.3731x over previous
//
#include <hip/hip_runtime.h>

// ---------------------------------------------------------------------------
// OracleAD2D: per-variable LSTM encoder -> temporal softmax pooling -> MHSA
//             -> per-variable LSTM decoder.  B=64, L=128, N=32, D=128, H=4.
//
// Round-9 (= r5 recurrent cores + r8 correctness fix, r8's poison removed):
//  * r8's 3x regression was a[wv] DYNAMIC register-array indexing in the
//    split pool/out-dot (scratch spill / cndmask cascade on every step).
//    Pool/out dot reverted to wave-0 chained MFMAs (constant indices).
//  * Zero-row broadcast KEPT (measured: bank conflicts 4.17M -> 2.08M):
//    A-frag lanes for rows =2,3 mod 4 (always zero) read shared row 2.
//  * dec keeps the r8 fix: inline out-projection writes C_star to its
//    OUTPUT region (C_star is the reference's 3rd output) and feeds the LSTM.
//  * 3 kernels: enc, attn, dec(+outproj); 256 blocks for enc/dec
//    (32 n x 8 b-tiles of 8), XCD swizzle n=blk&31, Whh resident as f16
//    B-fragments, bias as MFMA C operand, 1 intra-block barrier/step.
//  * MFMA layouts (m89/m91/m120-verified on gfx950):
//      A: lane holds A[m = lane&15][k = (lane>>4)*8 + j]   (8 f16)
//      B: lane holds B[n = lane&15][k = (lane>>4)*8 + j]   (8 f16)
//      D: lane reg r holds D[row = (lane>>4)*4 + r][col = lane&15]
// ---------------------------------------------------------------------------

typedef _Float16 h8  __attribute__((ext_vector_type(8)));
typedef _Float16 h4v __attribute__((ext_vector_type(4)));
typedef float    f4  __attribute__((ext_vector_type(4)));
typedef float    f2v __attribute__((ext_vector_type(2)));

#define DI __device__ __forceinline__

constexpr int NV  = 32;          // variables
constexpr int LT  = 128;         // sequence length
constexpr int DH  = 128;         // hidden
constexpr int GG  = 4 * DH;      // 512 gate rows
constexpr int BR  = 8;           // batch rows per block (enc/dec)
constexpr int NW  = 8;           // waves per block
constexpr int TPB = NW * 64;     // 512 threads
constexpr int HSTR = DH + 8;     // padded f16 row stride (16B-aligned)
constexpr float LOG2E = 1.4426950408889634f;

DI float rcp_(float x) { return __builtin_amdgcn_rcpf(x); }
DI float ex2_(float x) { return __builtin_amdgcn_exp2f(x); }

DI float tanh_(float x) {
    float xc = fminf(fmaxf(x, -20.0f), 20.0f);
    float E = ex2_(2.0f * LOG2E * xc);                  // e^{2x}
    return (E - 1.0f) * rcp_(E + 1.0f);
}

// Pre-scaled LSTM cell (scales folded into weights):
//   iv = -log2e*i, fv = -log2e*f, gv = 2log2e*g, ov = -log2e*o
DI float lstm_cell(float iv, float fv, float gv, float ov, float& c) {
    float Ai = ex2_(iv);                 // e^{-i}
    float Af = ex2_(fv);                 // e^{-f}
    float Bg = ex2_(gv);                 // e^{2g}
    float ai1 = 1.0f + Ai, af1 = 1.0f + Af, bg1 = 1.0f + Bg;
    float P = ai1 * bg1;
    float N = fmaf(c, P, (Bg - 1.0f) * af1);
    c = N * rcp_(P * af1);
    float cc = fminf(fmaxf(c, -20.0f), 20.0f);
    float Ec = ex2_(2.0f * LOG2E * cc);  // e^{2c}
    float Eo = ex2_(ov);                 // e^{-o}
    return (Ec - 1.0f) * rcp_((1.0f + Eo) * (1.0f + Ec)); // sig(o)*tanh(c)
}

DI h8 cvt8(f4 a, f4 b) {
    h8 r;
    r[0] = (_Float16)a[0]; r[1] = (_Float16)a[1];
    r[2] = (_Float16)a[2]; r[3] = (_Float16)a[3];
    r[4] = (_Float16)b[0]; r[5] = (_Float16)b[1];
    r[6] = (_Float16)b[2]; r[7] = (_Float16)b[3];
    return r;
}
DI h8 cvt8s(f4 a, f4 b, float s) {
    h8 r;
    r[0] = (_Float16)(a[0] * s); r[1] = (_Float16)(a[1] * s);
    r[2] = (_Float16)(a[2] * s); r[3] = (_Float16)(a[3] * s);
    r[4] = (_Float16)(b[0] * s); r[5] = (_Float16)(b[1] * s);
    r[6] = (_Float16)(b[2] * s); r[7] = (_Float16)(b[3] * s);
    return r;
}

// gate exp2 scales (torch order i,f,g,o)
__constant__ float GSC[4] = {-LOG2E, -LOG2E, 2.0f * LOG2E, -LOG2E};

// ---------------------------------------------------------------------------
// Encoder: 127 LSTM steps + online softmax pooling.  Writes C (B,N,D) f32.
// ---------------------------------------------------------------------------
__global__ __launch_bounds__(TPB, 2)
void enc_kernel(const float* __restrict__ X,      // (B,L,N)
                const float* __restrict__ Wih,    // (N,512)
                const float* __restrict__ Whh,    // (N,512,128)
                const float* __restrict__ bih,    // (N,512)
                const float* __restrict__ bhh,    // (N,512)
                const float* __restrict__ poolw,  // (N,128)
                float* __restrict__ Cout)         // (B,N,D)
{
    const int n    = blockIdx.x & 31;           // XCD swizzle: same n -> same XCD
    const int b0   = (blockIdx.x >> 5) * BR;
    const int tid  = threadIdx.x;
    const int wv   = tid >> 6;
    const int lane = tid & 63;
    const int quad = lane >> 4;
    const int l16  = lane & 15;
    const int dmy  = wv * 16 + l16;
    // zero-row broadcast: rows =2,3 mod 4 are always zero -> read shared row 2
    const int rowA = ((l16 & 3) < 2) ? l16 : 2;

    __shared__ _Float16 hbuf[2][16 * HSTR];
    __shared__ float xs[(LT - 1) * BR];
    __shared__ float pfin[2][BR];

    // --- preload B-fragments of Whh (f16, scaled by gate exp2 factor) ---
    h8 Wf[4][4];
    float wihr[4];
    f4 bsp[4];
#pragma unroll
    for (int g4 = 0; g4 < 4; ++g4) {
        const float s = GSC[g4];
        const int g = g4 * DH + dmy;
        const float* wrow = Whh + (size_t)(n * GG + g) * DH;
#pragma unroll
        for (int kc = 0; kc < 4; ++kc) {
            f4 w0 = *(const f4*)(wrow + kc * 32 + quad * 8);
            f4 w1 = *(const f4*)(wrow + kc * 32 + quad * 8 + 4);
            Wf[g4][kc] = cvt8s(w0, w1, s);
        }
        wihr[g4] = Wih[n * GG + g] * s;
        const float bb = (bih[n * GG + g] + bhh[n * GG + g]) * s;
        bsp[g4] = (f4){bb, bb, bb, bb};
    }
    // pool B-fragment: col 0 = pool_w * log2e (so p = exp2(s)), rest zero
    h8 Bp[4];
#pragma unroll
    for (int kc = 0; kc < 4; ++kc) {
        if (l16 == 0) {
            f4 p0 = *(const f4*)(poolw + n * DH + kc * 32 + quad * 8);
            f4 p1 = *(const f4*)(poolw + n * DH + kc * 32 + quad * 8 + 4);
            Bp[kc] = cvt8s(p0, p1, LOG2E);
        } else {
            Bp[kc] = (h8)(_Float16)0.0f;
        }
    }

    // --- stage X slab (8 b x 127 t) and zero both h buffers ---
    for (int i = tid; i < (LT - 1) * BR; i += TPB)      // i = t*8 + b
        xs[i] = X[((size_t)(b0 + (i & 7)) * LT + (i >> 3)) * NV + n];
    for (int i = tid; i < 2 * 16 * HSTR; i += TPB)
        ((_Float16*)hbuf)[i] = (_Float16)0.0f;
    __syncthreads();

    float cst[2]   = {0.f, 0.f};
    float lsum[2]  = {0.f, 0.f};
    float acc[2]   = {0.f, 0.f};
    float hprev[2] = {0.f, 0.f};

    for (int t = 0; t < LT - 1; ++t) {
        const _Float16* ab = hbuf[t & 1] + rowA * HSTR + quad * 8;
        h8 a[4];
#pragma unroll
        for (int kc = 0; kc < 4; ++kc)
            a[kc] = *(const h8*)(ab + kc * 32);

        f4 pre[4];
#pragma unroll
        for (int g4 = 0; g4 < 4; ++g4)
            pre[g4] = __builtin_amdgcn_mfma_f32_16x16x32_f16(
                a[0], Wf[g4][0], bsp[g4], 0, 0, 0);
#pragma unroll
        for (int kc = 1; kc < 4; ++kc)
#pragma unroll
            for (int g4 = 0; g4 < 4; ++g4)
                pre[g4] = __builtin_amdgcn_mfma_f32_16x16x32_f16(
                    a[kc], Wf[g4][kc], pre[g4], 0, 0, 0);

        // wave 0: pooling dot s^(t)[b] (pre-scaled by log2e) via extra tile
        if (wv == 0) {
            f4 sp = {0.f, 0.f, 0.f, 0.f};
#pragma unroll
            for (int kc = 0; kc < 4; ++kc)
                sp = __builtin_amdgcn_mfma_f32_16x16x32_f16(a[kc], Bp[kc], sp, 0, 0, 0);
            if (l16 == 0) {
                pfin[t & 1][quad * 2 + 0] = ex2_(sp[0]);
                pfin[t & 1][quad * 2 + 1] = ex2_(sp[1]);
            }
        }

        const f2v xv = *(const f2v*)(xs + t * BR + quad * 2);
        float hv[2];
#pragma unroll
        for (int r = 0; r < 2; ++r) {
            hv[r] = lstm_cell(fmaf(xv[r], wihr[0], pre[0][r]),
                              fmaf(xv[r], wihr[1], pre[1][r]),
                              fmaf(xv[r], wihr[2], pre[2][r]),
                              fmaf(xv[r], wihr[3], pre[3][r]), cst[r]);
        }

        _Float16* hn = hbuf[(t + 1) & 1];
#pragma unroll
        for (int r = 0; r < 2; ++r)
            hn[(quad * 4 + r) * HSTR + dmy] = (_Float16)hv[r];
        __syncthreads();

        // pooling update with p^(t) (from h^(t)) and hprev = h^(t)
        if (t > 0) {
#pragma unroll
            for (int r = 0; r < 2; ++r) {
                const float p = pfin[t & 1][quad * 2 + r];
                lsum[r] += p;
                acc[r] = fmaf(p, hprev[r], acc[r]);
            }
        }
#pragma unroll
        for (int r = 0; r < 2; ++r) hprev[r] = hv[r];
    }

    // tail: pool weight for h^(127) (staged in hbuf[(LT-1)&1])
    if (wv == 0) {
        const _Float16* ab = hbuf[(LT - 1) & 1] + rowA * HSTR + quad * 8;
        h8 a[4];
#pragma unroll
        for (int kc = 0; kc < 4; ++kc)
            a[kc] = *(const h8*)(ab + kc * 32);
        f4 sp = {0.f, 0.f, 0.f, 0.f};
#pragma unroll
        for (int kc = 0; kc < 4; ++kc)
            sp = __builtin_amdgcn_mfma_f32_16x16x32_f16(a[kc], Bp[kc], sp, 0, 0, 0);
        if (l16 == 0) {
            pfin[(LT - 1) & 1][quad * 2 + 0] = ex2_(sp[0]);
            pfin[(LT - 1) & 1][quad * 2 + 1] = ex2_(sp[1]);
        }
    }
    __syncthreads();
#pragma unroll
    for (int r = 0; r < 2; ++r) {
        const float p = pfin[(LT - 1) & 1][quad * 2 + r];
        lsum[r] += p;
        acc[r] = fmaf(p, hprev[r], acc[r]);
    }
#pragma unroll
    for (int r = 0; r < 2; ++r) {
        const int b = b0 + quad * 2 + r;
        Cout[((size_t)b * NV + n) * DH + dmy] = acc[r] * rcp_(lsum[r]);
    }
}

// ---------------------------------------------------------------------------
// Fused attention: one block per (b, head).  qkv proj + scores + softmax + PV
// all via MFMA.  Writes A (B,N,D) f32 (heads concatenated) to Astage.
// ---------------------------------------------------------------------------
constexpr int CS2 = DH + 8;     // f16 stride for staged C (16B-aligned rows)
constexpr int QS  = 40;         // f16 stride for q/k/vT/P (80 B rows, aligned)

__global__ __launch_bounds__(256)
void attn_kernel(const float* __restrict__ Cin,   // (B,N,D)
                 const float* __restrict__ Wqkv,  // (384,128)
                 const float* __restrict__ bqkv,  // (384)
                 float* __restrict__ Astage)      // (B,N,D)
{
    const int b    = blockIdx.x >> 2;
    const int hh   = blockIdx.x & 3;
    const int tid  = threadIdx.x;
    const int wv   = tid >> 6;          // 4 waves
    const int lane = tid & 63;
    const int quad = lane >> 4;
    const int l16  = lane & 15;

    __shared__ _Float16 Cb[NV][CS2];    // C tokens as f16 (A-operand layout)
    __shared__ _Float16 qs[NV][QS], ks[NV][QS], vT[NV][QS];
    __shared__ float    S[NV][NV + 1];
    __shared__ _Float16 P[NV][QS];

    // stage C[b] -> f16 LDS
    for (int i = tid; i < NV * DH / 4; i += 256) {
        const int nn = i >> 5, d4 = (i & 31) * 4;
        f4 v = *(const f4*)(Cin + ((size_t)b * NV + nn) * DH + d4);
        h4v hv4;
        hv4[0] = (_Float16)v[0]; hv4[1] = (_Float16)v[1];
        hv4[2] = (_Float16)v[2]; hv4[3] = (_Float16)v[3];
        *(h4v*)(&Cb[nn][d4]) = hv4;
    }
    __syncthreads();

    // --- qkv: wave wv computes sub-tile (m0,n0) of each of q, k, v ---
    const int m0 = (wv >> 1) * 16;      // token tile
    const int n0 = (wv & 1) * 16;       // column tile (within the head's 32)

    h8 a[4];
#pragma unroll
    for (int kc = 0; kc < 4; ++kc)
        a[kc] = *(const h8*)(&Cb[m0 + l16][kc * 32 + quad * 8]);

#pragma unroll
    for (int mat = 0; mat < 3; ++mat) {      // 0=q, 1=k, 2=v
        const int rbase = mat * DH + hh * 32;
        const float* wrow = Wqkv + (size_t)(rbase + n0 + l16) * DH;
        const float bias  = bqkv[rbase + n0 + l16];
        f4 acc = {bias, bias, bias, bias};
#pragma unroll
        for (int kc = 0; kc < 4; ++kc) {
            f4 w0 = *(const f4*)(wrow + kc * 32 + quad * 8);
            f4 w1 = *(const f4*)(wrow + kc * 32 + quad * 8 + 4);
            acc = __builtin_amdgcn_mfma_f32_16x16x32_f16(a[kc], cvt8(w0, w1), acc, 0, 0, 0);
        }
#pragma unroll
        for (int r = 0; r < 4; ++r) {
            const int tok = m0 + quad * 4 + r, col = n0 + l16;
            if (mat == 0)      qs[tok][col] = (_Float16)acc[r];
            else if (mat == 1) ks[tok][col] = (_Float16)acc[r];
            else               vT[col][tok] = (_Float16)acc[r];   // transposed
        }
    }
    __syncthreads();

    // --- scores: wave wv -> S tile (m0, n0), K = 32 head dims ---
    {
        h8 aq = *(const h8*)(&qs[m0 + l16][quad * 8]);
        h8 bk = *(const h8*)(&ks[n0 + l16][quad * 8]);
        f4 sc = {0.f, 0.f, 0.f, 0.f};
        sc = __builtin_amdgcn_mfma_f32_16x16x32_f16(aq, bk, sc, 0, 0, 0);
#pragma unroll
        for (int r = 0; r < 4; ++r)
            S[m0 + quad * 4 + r][n0 + l16] = sc[r] * 0.17677669529663687f; // 1/sqrt(32)
    }
    __syncthreads();

    // --- softmax per query row (32 threads) ---
    if (tid < NV) {
        float mx = -1e30f;
        for (int j = 0; j < NV; ++j) mx = fmaxf(mx, S[tid][j]);
        float l = 0.0f;
        float p[NV];
#pragma unroll
        for (int j = 0; j < NV; ++j) {
            p[j] = ex2_(LOG2E * (S[tid][j] - mx));
            l += p[j];
        }
        const float rl = rcp_(l);
#pragma unroll
        for (int j = 0; j < NV; ++j) P[tid][j] = (_Float16)(p[j] * rl);
    }
    __syncthreads();

    // --- PV: wave wv -> A tile (m0, n0), K = 32 keys ---
    {
        h8 ap = *(const h8*)(&P[m0 + l16][quad * 8]);
        h8 bv = *(const h8*)(&vT[n0 + l16][quad * 8]);
        f4 av = {0.f, 0.f, 0.f, 0.f};
        av = __builtin_amdgcn_mfma_f32_16x16x32_f16(ap, bv, av, 0, 0, 0);
#pragma unroll
        for (int r = 0; r < 4; ++r) {
            const int tok = m0 + quad * 4 + r;
            Astage[((size_t)b * NV + tok) * DH + hh * 32 + n0 + l16] = av[r];
        }
    }
}

// ---------------------------------------------------------------------------
// Decoder: inline out-projection (C* = A@Wo^T + bo; stored to the C_star
// OUTPUT region and fed to the LSTM), init h/c = tanh(Linear(C*)), 128
// zero-input LSTM steps; output dot via wave-0 chained MFMAs; recon
// buffered in LDS, bulk-written after the loop.
// ---------------------------------------------------------------------------
__global__ __launch_bounds__(TPB, 2)
void dec_kernel(const float* __restrict__ A,      // (B,N,D) attention output
                float* __restrict__ Cst,          // (B,N,D) C_star OUTPUT (=A region)
                const float* __restrict__ Wo,     // (128,128)
                const float* __restrict__ bo,     // (128)
                const float* __restrict__ ihW,    // (N,D,D)
                const float* __restrict__ ihb,    // (N,D)
                const float* __restrict__ icW,    // (N,D,D)
                const float* __restrict__ icb,    // (N,D)
                const float* __restrict__ Whh,    // (N,512,128)
                const float* __restrict__ bih,    // (N,512)
                const float* __restrict__ bhh,    // (N,512)
                const float* __restrict__ outW,   // (N,128)
                const float* __restrict__ outb,   // (N)
                float* __restrict__ recon,        // (B,127,N)
                float* __restrict__ pred)         // (B,N)
{
    const int n    = blockIdx.x & 31;           // XCD swizzle
    const int b0   = (blockIdx.x >> 5) * BR;
    const int tid  = threadIdx.x;
    const int wv   = tid >> 6;
    const int lane = tid & 63;
    const int quad = lane >> 4;
    const int l16  = lane & 15;
    const int dmy  = wv * 16 + l16;
    const int rowA = ((l16 & 3) < 2) ? l16 : 2;  // zero-row broadcast

    __shared__ _Float16 hbuf[2][16 * HSTR];
    __shared__ float obuf[LT - 1][BR];

    h8 Wf[4][4];
    f4 bsp[4];
#pragma unroll
    for (int g4 = 0; g4 < 4; ++g4) {
        const float s = GSC[g4];
        const int g = g4 * DH + dmy;
        const float* wrow = Whh + (size_t)(n * GG + g) * DH;
#pragma unroll
        for (int kc = 0; kc < 4; ++kc) {
            f4 w0 = *(const f4*)(wrow + kc * 32 + quad * 8);
            f4 w1 = *(const f4*)(wrow + kc * 32 + quad * 8 + 4);
            Wf[g4][kc] = cvt8s(w0, w1, s);
        }
        const float bb = (bih[n * GG + g] + bhh[n * GG + g]) * s;
        bsp[g4] = (f4){bb, bb, bb, bb};
    }
    // output B-fragment: col 0 = out_W (true scale), rest zero
    h8 Bo[4];
#pragma unroll
    for (int kc = 0; kc < 4; ++kc) {
        if (l16 == 0) {
            f4 p0 = *(const f4*)(outW + n * DH + kc * 32 + quad * 8);
            f4 p1 = *(const f4*)(outW + n * DH + kc * 32 + quad * 8 + 4);
            Bo[kc] = cvt8(p0, p1);
        } else {
            Bo[kc] = (h8)(_Float16)0.0f;
        }
    }
    const float ob = outb[n];

    // --- zero both h buffers; stage A rows (8 b) at rows (j>>1)*4+(j&1) ---
    for (int i = tid; i < 2 * 16 * HSTR; i += TPB)
        ((_Float16*)hbuf)[i] = (_Float16)0.0f;
    __syncthreads();
    if (tid < 256) {
        const int j = tid >> 5, d4 = (tid & 31) * 4;    // 8 rows x 32 f4
        const int row = (j >> 1) * 4 + (j & 1);
        f4 v = *(const f4*)(A + ((size_t)(b0 + j) * NV + n) * DH + d4);
        h4v hv4;
        hv4[0] = (_Float16)v[0]; hv4[1] = (_Float16)v[1];
        hv4[2] = (_Float16)v[2]; hv4[3] = (_Float16)v[3];
        *(h4v*)(&hbuf[0][row * HSTR + d4]) = hv4;
    }
    __syncthreads();

    // --- inline out-projection: cs = A @ Wo^T + bo -> hbuf[1] (f16) and
    //     the C_star OUTPUT region (f32).  In-place on the A region: all A
    //     reads finished at the staging barrier above. ---
    {
        const _Float16* ab = hbuf[0] + rowA * HSTR + quad * 8;
        h8 a[4];
#pragma unroll
        for (int kc = 0; kc < 4; ++kc)
            a[kc] = *(const h8*)(ab + kc * 32);
        const float bias = bo[dmy];
        f4 acc = {bias, bias, bias, bias};
        const float* wrow = Wo + (size_t)dmy * DH;
#pragma unroll
        for (int kc = 0; kc < 4; ++kc) {
            f4 w0 = *(const f4*)(wrow + kc * 32 + quad * 8);
            f4 w1 = *(const f4*)(wrow + kc * 32 + quad * 8 + 4);
            acc = __builtin_amdgcn_mfma_f32_16x16x32_f16(a[kc], cvt8(w0, w1), acc, 0, 0, 0);
        }
        __syncthreads();             // all A reads done before hbuf[1] write
#pragma unroll
        for (int r = 0; r < 2; ++r) {
            hbuf[1][(quad * 4 + r) * HSTR + dmy] = (_Float16)acc[r];
            // C_star output store (row quad*4+r holds batch b0+quad*2+r)
            Cst[((size_t)(b0 + quad * 2 + r) * NV + n) * DH + dmy] = acc[r];
        }
    }
    __syncthreads();

    // --- init matmuls: h0 = tanh(cs@ihW^T + ihb), c0 = tanh(cs@icW^T + icb) ---
    float cst[2], hv0[2];
    {
        const _Float16* ab = hbuf[1] + rowA * HSTR + quad * 8;
        h8 a[4];
#pragma unroll
        for (int kc = 0; kc < 4; ++kc)
            a[kc] = *(const h8*)(ab + kc * 32);
        const float bh = ihb[n * DH + dmy];
        const float bc = icb[n * DH + dmy];
        f4 Ph = {bh, bh, bh, bh};
        f4 Pc = {bc, bc, bc, bc};
        const float* hrow = ihW + (size_t)(n * DH + dmy) * DH;
        const float* crow = icW + (size_t)(n * DH + dmy) * DH;
#pragma unroll
        for (int kc = 0; kc < 4; ++kc) {
            f4 w0 = *(const f4*)(hrow + kc * 32 + quad * 8);
            f4 w1 = *(const f4*)(hrow + kc * 32 + quad * 8 + 4);
            Ph = __builtin_amdgcn_mfma_f32_16x16x32_f16(a[kc], cvt8(w0, w1), Ph, 0, 0, 0);
            f4 u0 = *(const f4*)(crow + kc * 32 + quad * 8);
            f4 u1 = *(const f4*)(crow + kc * 32 + quad * 8 + 4);
            Pc = __builtin_amdgcn_mfma_f32_16x16x32_f16(a[kc], cvt8(u0, u1), Pc, 0, 0, 0);
        }
#pragma unroll
        for (int r = 0; r < 2; ++r) {
            hv0[r] = tanh_(Ph[r]);
            cst[r] = tanh_(Pc[r]);
        }
    }
    __syncthreads();                 // all cs reads done before hbuf[0] write
#pragma unroll
    for (int r = 0; r < 2; ++r)
        hbuf[0][(quad * 4 + r) * HSTR + dmy] = (_Float16)hv0[r];
    __syncthreads();

    // --- 128 zero-input LSTM steps; iter t's A-frags are h^(t) ---
    for (int t = 0; t < LT; ++t) {
        const _Float16* ab = hbuf[t & 1] + rowA * HSTR + quad * 8;
        h8 a[4];
#pragma unroll
        for (int kc = 0; kc < 4; ++kc)
            a[kc] = *(const h8*)(ab + kc * 32);

        f4 pre[4];
#pragma unroll
        for (int g4 = 0; g4 < 4; ++g4)
            pre[g4] = __builtin_amdgcn_mfma_f32_16x16x32_f16(
                a[0], Wf[g4][0], bsp[g4], 0, 0, 0);
#pragma unroll
        for (int kc = 1; kc < 4; ++kc)
#pragma unroll
            for (int g4 = 0; g4 < 4; ++g4)
                pre[g4] = __builtin_amdgcn_mfma_f32_16x16x32_f16(
                    a[kc], Wf[g4][kc], pre[g4], 0, 0, 0);

        // wave 0: output dot o^(t)[b] = h^(t)[b].out_W + ob -> LDS obuf
        if (wv == 0 && t > 0) {
            f4 so = {0.f, 0.f, 0.f, 0.f};
#pragma unroll
            for (int kc = 0; kc < 4; ++kc)
                so = __builtin_amdgcn_mfma_f32_16x16x32_f16(a[kc], Bo[kc], so, 0, 0, 0);
            if (l16 == 0) {
                obuf[t - 1][quad * 2 + 0] = so[0] + ob;
                obuf[t - 1][quad * 2 + 1] = so[1] + ob;
            }
        }

        float hv[2];
#pragma unroll
        for (int r = 0; r < 2; ++r)
            hv[r] = lstm_cell(pre[0][r], pre[1][r], pre[2][r], pre[3][r], cst[r]);

        _Float16* hn = hbuf[(t + 1) & 1];
#pragma unroll
        for (int r = 0; r < 2; ++r)
            hn[(quad * 4 + r) * HSTR + dmy] = (_Float16)hv[r];
        __syncthreads();
    }

    // tail: o^(128) -> pred (h^(128) staged in hbuf[LT & 1] = hbuf[0])
    if (wv == 0) {
        const _Float16* ab = hbuf[LT & 1] + rowA * HSTR + quad * 8;
        h8 a[4];
#pragma unroll
        for (int kc = 0; kc < 4; ++kc)
            a[kc] = *(const h8*)(ab + kc * 32);
        f4 so = {0.f, 0.f, 0.f, 0.f};
#pragma unroll
        for (int kc = 0; kc < 4; ++kc)
            so = __builtin_amdgcn_mfma_f32_16x16x32_f16(a[kc], Bo[kc], so, 0, 0, 0);
        if (l16 == 0) {
            pred[(size_t)(b0 + quad * 2 + 0) * NV + n] = so[0] + ob;
            pred[(size_t)(b0 + quad * 2 + 1) * NV + n] = so[1] + ob;
        }
    }

    // bulk recon write from obuf (visible via the step-loop barriers)
    if (tid < LT - 1) {
#pragma unroll
        for (int b = 0; b < BR; ++b)
            recon[((size_t)(b0 + b) * (LT - 1) + tid) * NV + n] = obuf[tid][b];
    }
}

// ---------------------------------------------------------------------------
extern "C" void kernel_launch(void* const* d_in, const int* in_sizes, int n_in,
                              void* d_out, int out_size, void* d_ws, size_t ws_size,
                              hipStream_t stream) {
    (void)in_sizes; (void)n_in; (void)d_ws; (void)ws_size; (void)out_size;

    const float* X     = (const float*)d_in[0];
    const float* eWih  = (const float*)d_in[1];
    const float* eWhh  = (const float*)d_in[2];
    const float* ebih  = (const float*)d_in[3];
    const float* ebhh  = (const float*)d_in[4];
    const float* poolw = (const float*)d_in[5];
    // d_in[6] = pool_b: cancels inside softmax over t -> unused
    const float* Wqkv  = (const float*)d_in[7];
    const float* bqkv  = (const float*)d_in[8];
    const float* Wo    = (const float*)d_in[9];
    const float* bo    = (const float*)d_in[10];
    const float* dihW  = (const float*)d_in[11];
    const float* dihb  = (const float*)d_in[12];
    const float* dicW  = (const float*)d_in[13];
    const float* dicb  = (const float*)d_in[14];
    // d_in[15] = dec_Wih: decoder input is identically zero -> unused
    const float* dWhh  = (const float*)d_in[16];
    const float* dbih  = (const float*)d_in[17];
    const float* dbhh  = (const float*)d_in[18];
    const float* doutW = (const float*)d_in[19];
    const float* doutb = (const float*)d_in[20];

    float* out   = (float*)d_out;
    float* recon = out;                              // 64*127*32 = 260096
    float* pred  = out + 64 * 127 * 32;              // 2048
    float* Cstar = out + 64 * 127 * 32 + 64 * 32;    // C_star OUTPUT region
    // Pooled C staged in the recon+pred region; attention output A staged in
    // the C_star region; dec projects A in place (writes the true C_star
    // there) and then overwrites recon/pred.  Ordering via the stream.
    float* Cpool = out;
    float* Astg  = Cstar;

    enc_kernel<<<dim3(256), dim3(TPB), 0, stream>>>(
        X, eWih, eWhh, ebih, ebhh, poolw, Cpool);
    attn_kernel<<<dim3(256), dim3(256), 0, stream>>>(
        Cpool, Wqkv, bqkv, Astg);
    dec_kernel<<<dim3(256), dim3(TPB), 0, stream>>>(
        Astg, Cstar, Wo, bo, dihW, dihb, dicW, dicb, dWhh, dbih, dbhh,
        doutW, doutb, recon, pred);
}